// Round 6
// baseline (346.680 us; speedup 1.0000x reference)
//
#include <hip/hip_runtime.h>

#define BATCH 4096
#define TT 512
#define HH 64
#define BT 16      // batch rows per block (full 16-row MFMA tile, zero duplication)
#define XS 516     // x_s row stride in floats
#define HS 72      // h buffer row stride in bf16

typedef __attribute__((ext_vector_type(8))) short short8;
typedef __attribute__((ext_vector_type(4))) float floatx4;

__device__ __forceinline__ unsigned short f2bf(float f) {   // RNE f32->bf16
    unsigned u = __float_as_uint(f);
    u = u + 0x7FFFu + ((u >> 16) & 1u);
    return (unsigned short)(u >> 16);
}

// R1 structure (16 rows, 4 waves, 8 MFMA/wave -> 2 MFMA/row, no duplication)
// + R5 5-trans activations + LDS stamp-flag spin sync instead of __syncthreads.
// The 512 per-step barriers were ~550-680 cyc each (wall 1243-1341 cyc/step
// invariant across all occupancy configs R1-R5); a one-poll LDS spin is ~150.
__global__ __launch_bounds__(256, 1) void lstm_kernel(
    const float* __restrict__ x, const float* __restrict__ W_ih,
    const float* __restrict__ W_hh, const float* __restrict__ b_ih,
    const float* __restrict__ b_hh, const float* __restrict__ W_out,
    const float* __restrict__ b_out, float* __restrict__ out)
{
    __shared__ __align__(16) float x_s[BT * XS];
    __shared__ __align__(16) unsigned short hb0[BT * HS];   // h_k, k even
    __shared__ __align__(16) unsigned short hb1[BT * HS];   // h_k, k odd
    __shared__ __align__(16) float hf[BT * 65];
    __shared__ int sflag[4];                                // per-wave progress stamp

    const int tid = threadIdx.x;
    const int w = tid >> 6;       // wave 0..3 -> gate col-tiles {w,w+4,w+8,w+12}
    const int l = tid & 63;
    const int q = l >> 4;
    const int c = l & 15;
    const int n = 16 * w + c;     // hidden index this lane activates
    const int bbase = blockIdx.x * BT;
    volatile int* vf = sflag;

    if (tid < 4) sflag[tid] = 0;

    // stage x[bbase..bbase+15][0..511] into LDS, coalesced float4
    for (int i = 0; i < 8; ++i) {
        int flat = i * 256 + tid;              // 2048 float4s
        int row = flat >> 7, c4 = flat & 127;
        const float4* xg = reinterpret_cast<const float4*>(x + (size_t)(bbase + row) * TT);
        float4 v = xg[c4];
        *reinterpret_cast<float4*>(&x_s[row * XS + c4 * 4]) = v;
    }
    for (int i = tid; i < BT * HS; i += 256) { hb0[i] = 0; hb1[i] = 0; }

    // persistent B-fragments: W_hh rows for gates g = 64*t + n, bf16
    short8 bfr[4][2];
    float wih[4], bb[4];
    for (int t = 0; t < 4; ++t) {
        int g = 64 * t + n;
        wih[t] = W_ih[g];
        bb[t] = b_ih[g] + b_hh[g];
        for (int ks = 0; ks < 2; ++ks) {
            const float* wp = W_hh + g * 64 + ks * 32 + q * 8;
            short8 v;
            #pragma unroll
            for (int j = 0; j < 8; ++j) v[j] = (short)f2bf(wp[j]);
            bfr[t][ks] = v;
        }
    }

    float cst[4] = {0.f, 0.f, 0.f, 0.f};   // c-state, batch rows 4q+r, hidden n
    float hvr[4] = {0.f, 0.f, 0.f, 0.f};   // last h (for the head)

    const int aoff = c * HS + q * 8;
    const float L1 = 1.44269504089f;       // log2(e)
    const float L2 = 2.88539008178f;       // 2*log2(e)

    __syncthreads();   // one real barrier: staging + zeroed h0 + flags visible

    // iter k: wait flags>=k (h_k ready), read hb[k&1], write h_{k+1} to hb[(k+1)&1]
    auto step = [&](int k, const unsigned short* __restrict__ src,
                    unsigned short* __restrict__ dst, float xv) {
        while (!__all(vf[l & 3] >= k)) { }          // spin: h_k written by all waves
        short8 a0 = *reinterpret_cast<const short8*>(src + aoff);
        short8 a1 = *reinterpret_cast<const short8*>(src + aoff + 32);

        floatx4 acc[4];
        #pragma unroll
        for (int t = 0; t < 4; ++t)
            #pragma unroll
            for (int r = 0; r < 4; ++r) acc[t][r] = fmaf(xv, wih[t], bb[t]);

        #pragma unroll
        for (int t = 0; t < 4; ++t) {
            acc[t] = __builtin_amdgcn_mfma_f32_16x16x32_bf16(a0, bfr[t][0], acc[t], 0, 0, 0);
            acc[t] = __builtin_amdgcn_mfma_f32_16x16x32_bf16(a1, bfr[t][1], acc[t], 0, 0, 0);
        }

        #pragma unroll
        for (int r = 0; r < 4; ++r) {
            float gi = acc[0][r], gf = acc[1][r], gg = acc[2][r], go = acc[3][r];
            float ei = __builtin_amdgcn_exp2f(-L1 * gi);
            float ef = __builtin_amdgcn_exp2f(-L1 * gf);
            float eg = __builtin_amdgcn_exp2f( L2 * gg);
            float eo = __builtin_amdgcn_exp2f(-L1 * go);
            float pf1 = 1.f + ef, pig = (1.f + ei) * (1.f + eg);
            float num = fmaf(cst[r], pig, (eg - 1.f) * pf1);
            cst[r] = num * __builtin_amdgcn_rcpf(pf1 * pig);
            float ec = __builtin_amdgcn_exp2f(L2 * cst[r]);
            float hv = (ec - 1.f) * __builtin_amdgcn_rcpf((1.f + eo) * (1.f + ec));
            hvr[r] = hv;
            dst[(4 * q + r) * HS + n] = f2bf(hv);
        }
        __threadfence_block();                      // drain h writes (lgkmcnt)
        if (l == 0) vf[w] = k + 1;                  // publish progress
    };

    // NOTE: lane's x rows are 4q+r; prefetch 4 timesteps per row as float4
    for (int k4 = 0; k4 < TT; k4 += 4) {
        float4 xq[4];
        #pragma unroll
        for (int r = 0; r < 4; ++r)
            xq[r] = *reinterpret_cast<const float4*>(&x_s[(4 * q + r) * XS + k4]);
        // xv must be per-accumulator-row; acc init above uses one xv — fix: pass
        // per-row via array. (step uses xv for all rows; see xrow trick below)
        // -- handled by specializing: we re-expand acc init inside step via xq.
        (void)xq;
        // unrolled 4 steps with explicit buffers
        {
            // step bodies inlined to use per-row x values
            #pragma unroll
            for (int u = 0; u < 4; ++u) {
                int k = k4 + u;
                const unsigned short* src = (k & 1) ? hb1 : hb0;
                unsigned short* dst = (k & 1) ? hb0 : hb1;
                while (!__all(vf[l & 3] >= k)) { }
                short8 a0 = *reinterpret_cast<const short8*>(src + aoff);
                short8 a1 = *reinterpret_cast<const short8*>(src + aoff + 32);

                floatx4 acc[4];
                #pragma unroll
                for (int t = 0; t < 4; ++t)
                    #pragma unroll
                    for (int r = 0; r < 4; ++r)
                        acc[t][r] = fmaf((&xq[r].x)[u], wih[t], bb[t]);

                #pragma unroll
                for (int t = 0; t < 4; ++t) {
                    acc[t] = __builtin_amdgcn_mfma_f32_16x16x32_bf16(a0, bfr[t][0], acc[t], 0, 0, 0);
                    acc[t] = __builtin_amdgcn_mfma_f32_16x16x32_bf16(a1, bfr[t][1], acc[t], 0, 0, 0);
                }

                #pragma unroll
                for (int r = 0; r < 4; ++r) {
                    float gi = acc[0][r], gf = acc[1][r], gg = acc[2][r], go = acc[3][r];
                    float ei = __builtin_amdgcn_exp2f(-L1 * gi);
                    float ef = __builtin_amdgcn_exp2f(-L1 * gf);
                    float eg = __builtin_amdgcn_exp2f( L2 * gg);
                    float eo = __builtin_amdgcn_exp2f(-L1 * go);
                    float pf1 = 1.f + ef, pig = (1.f + ei) * (1.f + eg);
                    float num = fmaf(cst[r], pig, (eg - 1.f) * pf1);
                    cst[r] = num * __builtin_amdgcn_rcpf(pf1 * pig);
                    float ec = __builtin_amdgcn_exp2f(L2 * cst[r]);
                    float hv = (ec - 1.f) * __builtin_amdgcn_rcpf((1.f + eo) * (1.f + ec));
                    hvr[r] = hv;
                    dst[(4 * q + r) * HS + n] = f2bf(hv);
                }
                __threadfence_block();
                if (l == 0) vf[w] = k + 1;
            }
        }
    }

    #pragma unroll
    for (int r = 0; r < 4; ++r) hf[(4 * q + r) * 65 + n] = hvr[r];
    __syncthreads();

    // head: out[b][o] = sum_n hf[b][n]*W_out[o][n] + b_out[o]
    if (tid < BT * 3) {
        int row = tid / 3, o = tid % 3;
        float s = b_out[o];
        #pragma unroll 8
        for (int k = 0; k < HH; ++k) s = fmaf(hf[row * 65 + k], W_out[o * 64 + k], s);
        out[(size_t)(bbase + row) * 3 + o] = s;
    }
}

extern "C" void kernel_launch(void* const* d_in, const int* in_sizes, int n_in,
                              void* d_out, int out_size, void* d_ws, size_t ws_size,
                              hipStream_t stream) {
    const float* x     = (const float*)d_in[0];
    const float* W_ih  = (const float*)d_in[1];
    const float* W_hh  = (const float*)d_in[2];
    const float* b_ih  = (const float*)d_in[3];
    const float* b_hh  = (const float*)d_in[4];
    const float* W_out = (const float*)d_in[5];
    const float* b_out = (const float*)d_in[6];
    float* out = (float*)d_out;
    hipLaunchKernelGGL(lstm_kernel, dim3(BATCH / BT), dim3(256), 0, stream,
                       x, W_ih, W_hh, b_ih, b_hh, W_out, b_out, out);
}